// Round 3
// baseline (275.812 us; speedup 1.0000x reference)
//
#include <hip/hip_runtime.h>

#define DEVFN __device__ __forceinline__

typedef unsigned short u16;
typedef __attribute__((ext_vector_type(8))) unsigned short u16x8;
typedef __attribute__((ext_vector_type(4))) unsigned short u16x4;
typedef __attribute__((ext_vector_type(8))) __bf16 bf16x8;
typedef __attribute__((ext_vector_type(4))) float f32x4;

// ---------- helpers ----------
DEVFN u16 f2bf_hw(float f) {  // hardware RNE convert (single v_cvt)
    return __builtin_bit_cast(u16, (__bf16)f);
}

DEVFN float bf2f(u16 h) {
    unsigned u = (unsigned)h << 16;
    return __builtin_bit_cast(float, u);
}

DEVFN bf16x8 ldfrag(const u16* p) {
    return __builtin_bit_cast(bf16x8, *(const u16x8*)p);
}

DEVFN f32x4 mfma16(bf16x8 a, bf16x8 b, f32x4 c) {
    return __builtin_amdgcn_mfma_f32_16x16x32_bf16(a, b, c, 0, 0, 0);
}

// async global->LDS, 16B per lane; l must be the wave-uniform base
DEVFN void async16(const u16* g, u16* l) {
    __builtin_amdgcn_global_load_lds(
        (const __attribute__((address_space(1))) void*)g,
        (__attribute__((address_space(3))) void*)l, 16, 0, 0);
}

// ---------- fp32->bf16 converts + mask compaction, ONE dispatch ----------
__global__ __launch_bounds__(256) void conv_all(const float* __restrict__ y,
                                                const float* __restrict__ w0,
                                                const float* __restrict__ w1,
                                                const float* __restrict__ w2,
                                                const float* __restrict__ w3,
                                                u16* __restrict__ yb,
                                                u16* __restrict__ wb,
                                                const int* __restrict__ mask,
                                                int* __restrict__ idx,
                                                int* __restrict__ cnt) {
    const int b = blockIdx.x;
    if (b >= 12288) {
        const int wave = threadIdx.x >> 6, lane = threadIdx.x & 63;
        for (int bb = wave; bb < 8; bb += 4) {
            const int* m = mask + bb * 1024;
            int* ib = idx + bb * 1024;
            int base = 0;
            for (int t = 0; t < 16; ++t) {
                const int pos = t * 64 + lane;
                const int valid = (m[pos] == 0) ? 1 : 0;
                const unsigned long long bal = __ballot(valid);
                const int pre = __popcll(bal & ((1ull << lane) - 1ull));
                if (valid) ib[base + pre] = pos;
                base += (int)__popcll(bal);
            }
            if (lane == 0) cnt[bb] = base;
            for (int i = base + lane; i < 1024; i += 64) ib[i] = 0;  // safe pad
        }
        return;
    }
    const float* src;
    u16* dst;
    int i;
    if (b < 8192) {
        src = y; dst = yb;
        i = b * 1024 + threadIdx.x * 4;
    } else {
        const int g = (b - 8192) >> 10;
        src = g == 0 ? w0 : (g == 1 ? w1 : (g == 2 ? w2 : w3));
        dst = wb + (size_t)g * 1024 * 1024;
        i = ((b - 8192) & 1023) * 1024 + threadIdx.x * 4;
    }
    const float4 v = *(const float4*)&src[i];
    u16x4 o;
    o.x = f2bf_hw(v.x); o.y = f2bf_hw(v.y);
    o.z = f2bf_hw(v.z); o.w = f2bf_hw(v.w);
    *(u16x4*)&dst[i] = o;
}

// ---------- 256x256 GEMM with READ-AHEAD-ONE-PHASE pipeline ----------
// Round-3 theory: rounds 0-2 (29-38% MfmaUtil) issued ds_reads and consumed
// them in the SAME phase -> lgkm wait serializes LDS service with MFMA.
// Here each phase issues the reads for the NEXT quadrant; the compiler's
// dependency-based lgkmcnt before the MFMAs then waits only on reads issued
// one phase earlier (already serviced during the previous MFMA cluster).
// Per-phase read counts {4,8,0,12} (matches m201's "4 or 8 ... 12" note).
//
// Geometry: 8 waves = 2M(wr) x 4N(wc); per-wave C = 128x64 (mi0-7 x ni0-3).
// Quadrants: Q1 mi0-3xni0-1, Q2 mi0-3xni2-3, Q3 mi4-7xni0-1, Q4 mi4-7xni2-3
// (each 16 MFMA). Reads: afE(mi0-3) used Q1,Q2; afL(mi4-7) Q3,Q4;
// bf01 Q1,Q3; bf23 Q2,Q4.
// Issue (one ahead of use): p1: bf23(t); p2: af47(t); p3: none;
//                           p4: af03(t+1)+bf01(t+1)  [from buf^1].
// Stage ledger (half-tile = 2 gloads; (t+2) -> buf(t); WAR-safe points:
//  A-halves of t consumed by Q3-MFMA, published by p3's trailing barrier ->
//  A(t+2) stageable from p4(t). B-half0/1 consumed by Q1/Q2, published by
//  p1/p2 trailing barriers -> B(t+2) stageable from p3(t)):
//   p1(t): A1(t+1) [buf^1; old = (t-1).A1, consumed Q3/Q4(t-1), published]
//   p3(t): B0(t+2)   p4(t): B1(t+2) + A0(t+2)
// vmcnt(2) at end-p3 (newest 2 = B0(t+2) in flight; A1(t+1) and older done
// -> tile t+1 fully resident before p4's reads). Tail t>=NT-2: vmcnt(0).
// Swizzle: identical both-sides slot-XOR as rounds 1-2 (0 conflicts).
// K ascending in 32-chunks -> accumulation order identical (absmax stable).
__global__ __launch_bounds__(512, 2) void gemm9(const u16* __restrict__ A,
                                                const u16* __restrict__ Bt,
                                                const float* __restrict__ b0,
                                                const float* __restrict__ b1,
                                                const float* __restrict__ b2,
                                                u16* __restrict__ C0,
                                                u16* __restrict__ C1,
                                                u16* __restrict__ C2,
                                                int K, int NBX) {
    __shared__ u16 lds[2][2][2][8192];  // [buf][A=0/B=1][half][128r x 64k]
    const int NT = K >> 6;
    const int tid = threadIdx.x;
    const int wave = tid >> 6, lane = tid & 63;
    const int quad = lane >> 4, l16 = lane & 15;
    const int wr = wave >> 2;  // 0..1: A-half / M 128-block
    const int wc = wave & 3;   // 0..3: N 64-block; B-half = wc>>1
    // XCD-bijective chunked swizzle (grid 384 % 8 == 0)
    const int nwg = gridDim.x, cpx = nwg >> 3;
    const int sb = (blockIdx.x & 7) * cpx + (blockIdx.x >> 3);
    const int bx = sb % NBX, by = sb / NBX;
    const int m0 = by * 256, n0 = bx * 256;
    // staging: per-thread pre-swizzled source, linear LDS dest
    const int sr = lane >> 3, sc = lane & 7;
    const int scs = (sc ^ sr) << 3;
    const u16* Ag = A + (size_t)(m0 + wave * 8 + sr) * K + scs;
    const u16* Bg = Bt + (size_t)(n0 + wave * 8 + sr) * K + scs;
    const size_t h64 = (size_t)64 * K;  // 64-row step
    // read-side swizzled k-slot; kh=1 -> swz ^ 32
    const int swz = (quad ^ (l16 & 7)) << 3;
    const int brow = (wc & 1) * 64;  // row offset inside B-half

#define STAGE(gp, lp)                                      \
    do {                                                   \
        async16((gp), (lp) + wave * 512);                  \
        async16((gp) + h64, (lp) + 4096 + wave * 512);     \
    } while (0)
#define RD_A(dst, bf, mi)                                                     \
    do {                                                                      \
        dst[0] = ldfrag(&lds[bf][0][wr][((mi) * 16 + l16) * 64 + swz]);       \
        dst[1] = ldfrag(&lds[bf][0][wr][((mi) * 16 + l16) * 64 + (swz ^ 32)]);\
    } while (0)
#define RD_B(dst, bf, ni)                                                         \
    do {                                                                          \
        dst[0] = ldfrag(&lds[bf][1][wc >> 1][(brow + (ni) * 16 + l16) * 64 + swz]);\
        dst[1] = ldfrag(                                                          \
            &lds[bf][1][wc >> 1][(brow + (ni) * 16 + l16) * 64 + (swz ^ 32)]);    \
    } while (0)

    f32x4 acc[8][4] = {};
    bf16x8 afE[4][2], afL[4][2], bfr[4][2];

    // prologue: tile0 all 4 half-tiles, tile1 B0,B1,A0 (A1(1) comes at p1(0))
    STAGE(Ag, &lds[0][0][0][0]);                 // A0(0)
    STAGE(Ag + 2 * h64, &lds[0][0][1][0]);       // A1(0)
    STAGE(Bg, &lds[0][1][0][0]);                 // B0(0)
    STAGE(Bg + 2 * h64, &lds[0][1][1][0]);       // B1(0)
    STAGE(Bg + 64, &lds[1][1][0][0]);            // B0(1)
    STAGE(Bg + 2 * h64 + 64, &lds[1][1][1][0]);  // B1(1)
    STAGE(Ag + 64, &lds[1][0][0][0]);            // A0(1)
    asm volatile("s_waitcnt vmcnt(6)" ::: "memory");  // tile0 resident
    __builtin_amdgcn_s_barrier();
    // pre-reads for p1(0): af03(0), bf01(0)
    #pragma unroll
    for (int mi = 0; mi < 4; ++mi) RD_A(afE[mi], 0, mi);
    #pragma unroll
    for (int ni = 0; ni < 2; ++ni) RD_B(bfr[ni], 0, ni);

    for (int t = 0; t < NT; ++t) {
        const int buf = t & 1;
        // ---- p1: MFMA Q1 (afE x bf01); issue bf23(t); stage A1(t+1) ----
        #pragma unroll
        for (int ni = 2; ni < 4; ++ni) RD_B(bfr[ni], buf, ni);
        if (t + 1 < NT)
            STAGE(Ag + 2 * h64 + (size_t)(t + 1) * 64, &lds[buf ^ 1][0][1][0]);
        __builtin_amdgcn_s_barrier();
        __builtin_amdgcn_s_setprio(1);
        #pragma unroll
        for (int mi = 0; mi < 4; ++mi)
            #pragma unroll
            for (int ni = 0; ni < 2; ++ni) {
                acc[mi][ni] = mfma16(afE[mi][0], bfr[ni][0], acc[mi][ni]);
                acc[mi][ni] = mfma16(afE[mi][1], bfr[ni][1], acc[mi][ni]);
            }
        __builtin_amdgcn_s_setprio(0);
        __builtin_amdgcn_s_barrier();
        // ---- p2: MFMA Q2 (afE x bf23); issue af47(t) ----
        #pragma unroll
        for (int mi = 0; mi < 4; ++mi) RD_A(afL[mi], buf, mi + 4);
        __builtin_amdgcn_s_barrier();
        __builtin_amdgcn_s_setprio(1);
        #pragma unroll
        for (int mi = 0; mi < 4; ++mi)
            #pragma unroll
            for (int ni = 2; ni < 4; ++ni) {
                acc[mi][ni] = mfma16(afE[mi][0], bfr[ni][0], acc[mi][ni]);
                acc[mi][ni] = mfma16(afE[mi][1], bfr[ni][1], acc[mi][ni]);
            }
        __builtin_amdgcn_s_setprio(0);
        __builtin_amdgcn_s_barrier();
        // ---- p3: MFMA Q3 (afL x bf01); stage B0(t+2); vmcnt checkpoint ----
        if (t + 2 < NT) STAGE(Bg + (size_t)(t + 2) * 64, &lds[buf][1][0][0]);
        __builtin_amdgcn_s_barrier();
        __builtin_amdgcn_s_setprio(1);
        #pragma unroll
        for (int mi = 0; mi < 4; ++mi)
            #pragma unroll
            for (int ni = 0; ni < 2; ++ni) {
                acc[mi + 4][ni] = mfma16(afL[mi][0], bfr[ni][0], acc[mi + 4][ni]);
                acc[mi + 4][ni] = mfma16(afL[mi][1], bfr[ni][1], acc[mi + 4][ni]);
            }
        __builtin_amdgcn_s_setprio(0);
        if (t < NT - 2)
            asm volatile("s_waitcnt vmcnt(2)" ::: "memory");
        else
            asm volatile("s_waitcnt vmcnt(0)" ::: "memory");
        __builtin_amdgcn_s_barrier();
        // ---- p4: MFMA Q4 (afL x bf23); issue af03(t+1)+bf01(t+1);
        //          stage B1(t+2) + A0(t+2) ----
        if (t + 1 < NT) {
            #pragma unroll
            for (int mi = 0; mi < 4; ++mi) RD_A(afE[mi], buf ^ 1, mi);
            #pragma unroll
            for (int ni = 0; ni < 2; ++ni) RD_B(bfr[ni], buf ^ 1, ni);
        }
        if (t + 2 < NT) {
            STAGE(Bg + 2 * h64 + (size_t)(t + 2) * 64, &lds[buf][1][1][0]);
            STAGE(Ag + (size_t)(t + 2) * 64, &lds[buf][0][0][0]);
        }
        __builtin_amdgcn_s_barrier();
        __builtin_amdgcn_s_setprio(1);
        #pragma unroll
        for (int mi = 0; mi < 4; ++mi)
            #pragma unroll
            for (int ni = 2; ni < 4; ++ni) {
                acc[mi + 4][ni] = mfma16(afL[mi][0], bfr[ni][0], acc[mi + 4][ni]);
                acc[mi + 4][ni] = mfma16(afL[mi][1], bfr[ni][1], acc[mi + 4][ni]);
            }
        __builtin_amdgcn_s_setprio(0);
        __builtin_amdgcn_s_barrier();
    }
#undef STAGE
#undef RD_A
#undef RD_B
    // epilogue: bias + bf16 store; col>>10 selects q/k/v buffer
    const int wrow = m0 + wr * 128 + quad * 4;
    #pragma unroll
    for (int ni = 0; ni < 4; ++ni) {
        const int col = n0 + wc * 64 + ni * 16 + l16;
        const int cs = col >> 10;
        const int c = col & 1023;
        const float* bp = cs == 0 ? b0 : (cs == 1 ? b1 : b2);
        u16* cp = cs == 0 ? C0 : (cs == 1 ? C1 : C2);
        const float bb = bp[c];
        #pragma unroll
        for (int mi = 0; mi < 8; ++mi)
            #pragma unroll
            for (int r = 0; r < 4; ++r) {
                const int row = wrow + mi * 16 + r;
                cp[(size_t)row * 1024 + c] = f2bf_hw(acc[mi][ni][r] + bb);
            }
    }
}

// ---------- pipelined 256x128 GEMM (round-2 kernel, kept for M-proj) ----------
__global__ __launch_bounds__(512, 2) void gemm8b(const u16* __restrict__ A,
                                                 const u16* __restrict__ Bt,
                                                 const float* __restrict__ b0,
                                                 const float* __restrict__ b1,
                                                 const float* __restrict__ b2,
                                                 u16* __restrict__ C0,
                                                 u16* __restrict__ C1,
                                                 u16* __restrict__ C2,
                                                 int K, int NBX) {
    __shared__ u16 lds[2][24576];  // per buf: A @0 (16384), B @16384 (8192)
    const int NT = K >> 6;
    const int tid = threadIdx.x;
    const int wave = tid >> 6, lane = tid & 63;
    const int quad = lane >> 4, l16 = lane & 15;
    const int wm = wave >> 1, wn = wave & 1;
    const int nwg = gridDim.x, cpx = nwg >> 3;
    const int sb = (blockIdx.x & 7) * cpx + (blockIdx.x >> 3);
    const int bx = sb % NBX, by = sb / NBX;
    const int m0 = by * 256, n0 = bx * 128;
    const int sr = lane >> 3, sc = lane & 7;
    const int scs = (sc ^ sr) << 3;
    const u16* Ag = A + (size_t)(m0 + wave * 8 + sr) * K + scs;
    const u16* Bg = Bt + (size_t)(n0 + wave * 8 + sr) * K + scs;
    const size_t rstep = (size_t)64 * K;
    const int swz = (quad ^ (l16 & 7)) << 3;
    const int rofA = (wm * 64 + l16) * 64 + swz;
    const int rofB = (wn * 64 + l16) * 64 + swz;

#define STAGE(gp, lp)                                        \
    do {                                                     \
        async16((gp), (lp) + wave * 512);                    \
        async16((gp) + rstep, (lp) + 4096 + wave * 512);     \
    } while (0)

    f32x4 acc[4][4] = {};

    STAGE(Ag, &lds[0][0]);
    STAGE(Ag + 2 * rstep, &lds[0][8192]);
    STAGE(Bg, &lds[0][16384]);
    STAGE(Ag + 64, &lds[1][0]);
    STAGE(Ag + 2 * rstep + 64, &lds[1][8192]);
    asm volatile("s_waitcnt vmcnt(4)" ::: "memory");
    __builtin_amdgcn_s_barrier();

    for (int t = 0; t < NT; ++t) {
        const int buf = t & 1;
        const u16* Ar = &lds[buf][0];
        const u16* Br = &lds[buf][16384];
        bf16x8 af[4][2], bfr[4][2];
        #pragma unroll
        for (int mi = 0; mi < 4; ++mi) {
            af[mi][0] = ldfrag(Ar + mi * 1024 + rofA);
            af[mi][1] = ldfrag(Ar + mi * 1024 + (rofA ^ 32));
        }
        #pragma unroll
        for (int ni = 0; ni < 2; ++ni) {
            bfr[ni][0] = ldfrag(Br + ni * 1024 + rofB);
            bfr[ni][1] = ldfrag(Br + ni * 1024 + (rofB ^ 32));
        }
        if (t + 1 < NT) STAGE(Bg + (t + 1) * 64, &lds[buf ^ 1][16384]);
        __builtin_amdgcn_s_barrier();
        asm volatile("s_waitcnt lgkmcnt(0)" ::: "memory");
        __builtin_amdgcn_s_setprio(1);
        #pragma unroll
        for (int mi = 0; mi < 4; ++mi)
            #pragma unroll
            for (int ni = 0; ni < 2; ++ni) {
                acc[mi][ni] = mfma16(af[mi][0], bfr[ni][0], acc[mi][ni]);
                acc[mi][ni] = mfma16(af[mi][1], bfr[ni][1], acc[mi][ni]);
            }
        __builtin_amdgcn_s_setprio(0);
        __builtin_amdgcn_s_barrier();
        #pragma unroll
        for (int ni = 2; ni < 4; ++ni) {
            bfr[ni][0] = ldfrag(Br + ni * 1024 + rofB);
            bfr[ni][1] = ldfrag(Br + ni * 1024 + (rofB ^ 32));
        }
        if (t + 2 < NT) {
            STAGE(Ag + (t + 2) * 64, &lds[buf][0]);
            STAGE(Ag + 2 * rstep + (t + 2) * 64, &lds[buf][8192]);
        }
        __builtin_amdgcn_s_barrier();
        asm volatile("s_waitcnt lgkmcnt(0)" ::: "memory");
        __builtin_amdgcn_s_setprio(1);
        #pragma unroll
        for (int mi = 0; mi < 4; ++mi)
            #pragma unroll
            for (int ni = 2; ni < 4; ++ni) {
                acc[mi][ni] = mfma16(af[mi][0], bfr[ni][0], acc[mi][ni]);
                acc[mi][ni] = mfma16(af[mi][1], bfr[ni][1], acc[mi][ni]);
            }
        __builtin_amdgcn_s_setprio(0);
        if (t < NT - 2)
            asm volatile("s_waitcnt vmcnt(4)" ::: "memory");
        else
            asm volatile("s_waitcnt vmcnt(0)" ::: "memory");
        __builtin_amdgcn_s_barrier();
    }
#undef STAGE
    const int wrow = m0 + wm * 64 + quad * 4;
    #pragma unroll
    for (int ni = 0; ni < 4; ++ni) {
        const int col = n0 + wn * 64 + ni * 16 + l16;
        const int cs = col >> 10;
        const int c = col & 1023;
        const float* bp = cs == 0 ? b0 : (cs == 1 ? b1 : b2);
        u16* cp = cs == 0 ? C0 : (cs == 1 ? C1 : C2);
        const float bb = bp[c];
        #pragma unroll
        for (int mi = 0; mi < 4; ++mi)
            #pragma unroll
            for (int r = 0; r < 4; ++r) {
                const int row = wrow + mi * 16 + r;
                cp[(size_t)row * 1024 + c] = f2bf_hw(acc[mi][ni][r] + bb);
            }
    }
}

// ---------- flash attention over COMPACTED K/V, in-kernel V transpose ----------
__global__ __launch_bounds__(256) void attn(const u16* __restrict__ qb,
                                            const u16* __restrict__ kb,
                                            const u16* __restrict__ vb,
                                            const int* __restrict__ idxb,
                                            const int* __restrict__ cntb,
                                            u16* __restrict__ attb) {
    const int lin = blockIdx.x;
    const int xcd = lin & 7, slot = lin >> 3;          // slot 0..127
    const int bh = xcd * 16 + (slot >> 3);
    const int q0 = (slot & 7) * 128;
    const int bb = bh >> 4, h = bh & 15;
    const int tid = threadIdx.x, wave = tid >> 6, lane = tid & 63;
    const int quad = lane >> 4, l16 = lane & 15;
    __shared__ u16 lK[64 * 72];
    __shared__ u16 lV[64 * 72];
    __shared__ u16 lP[128 * 72];

    const int cn = cntb[bb];
    const int kEnd = (cn + 63) & ~63;
    const int* ib = idxb + bb * 1024;

    bf16x8 aq[2][2];
    #pragma unroll
    for (int rg = 0; rg < 2; ++rg) {
        const int qrow = q0 + wave * 32 + rg * 16 + l16;
        const u16* qp = qb + (size_t)(bb * 1024 + qrow) * 1024 + h * 64 + quad * 8;
        aq[rg][0] = ldfrag(qp);
        aq[rg][1] = ldfrag(qp + 32);
    }

    f32x4 o[2][4] = {};
    float ps_acc[2][4] = {};

    const int srow = tid >> 3, scol = (tid & 7) * 8;
    const u16* kbase = kb + (size_t)(bb * 1024) * 1024 + h * 64 + scol;
    const u16* vbase = vb + (size_t)(bb * 1024) * 1024 + h * 64 + scol;

    int gi0 = ib[srow], gi1 = ib[srow + 32];
    u16x8 nk0 = *(const u16x8*)(kbase + (size_t)gi0 * 1024);
    u16x8 nk1 = *(const u16x8*)(kbase + (size_t)gi1 * 1024);
    u16x8 nv0 = *(const u16x8*)(vbase + (size_t)gi0 * 1024);
    u16x8 nv1 = *(const u16x8*)(vbase + (size_t)gi1 * 1024);

    const float C = 0.18033688011112043f;  // 0.125 * log2(e)

    for (int kt = 0; kt < kEnd; kt += 64) {
        __syncthreads();
        *(u16x8*)&lK[srow * 72 + scol] = nk0;
        *(u16x8*)&lK[(srow + 32) * 72 + scol] = nk1;
        #pragma unroll
        for (int j = 0; j < 8; ++j) {
            lV[(scol + j) * 72 + srow] = nv0[j];
            lV[(scol + j) * 72 + srow + 32] = nv1[j];
        }
        __syncthreads();
        const int ktn = kt + 64;
        if (ktn < kEnd) {
            gi0 = ib[ktn + srow]; gi1 = ib[ktn + srow + 32];
            nk0 = *(const u16x8*)(kbase + (size_t)gi0 * 1024);
            nk1 = *(const u16x8*)(kbase + (size_t)gi1 * 1024);
            nv0 = *(const u16x8*)(vbase + (size_t)gi0 * 1024);
            nv1 = *(const u16x8*)(vbase + (size_t)gi1 * 1024);
        }

        bf16x8 kf[4][2];
        #pragma unroll
        for (int n = 0; n < 4; ++n) {
            kf[n][0] = ldfrag(&lK[(n * 16 + l16) * 72 + quad * 8]);
            kf[n][1] = ldfrag(&lK[(n * 16 + l16) * 72 + 32 + quad * 8]);
        }
        f32x4 s[2][4];
        #pragma unroll
        for (int rg = 0; rg < 2; ++rg)
            #pragma unroll
            for (int n = 0; n < 4; ++n) {
                f32x4 t = {};
                t = mfma16(aq[rg][0], kf[n][0], t);
                t = mfma16(aq[rg][1], kf[n][1], t);
                s[rg][n] = t;
            }
        float bias[4];
        #pragma unroll
        for (int n = 0; n < 4; ++n)
            bias[n] = (kt + n * 16 + l16 < cn) ? 0.0f : -1e9f;
        #pragma unroll
        for (int rg = 0; rg < 2; ++rg)
            #pragma unroll
            for (int n = 0; n < 4; ++n)
                #pragma unroll
                for (int r = 0; r < 4; ++r) {
                    const float p =
                        __builtin_amdgcn_exp2f(__builtin_fmaf(s[rg][n][r], C, bias[n]));
                    ps_acc[rg][r] += p;
                    lP[(wave * 32 + rg * 16 + quad * 4 + r) * 72 + n * 16 + l16] =
                        f2bf_hw(p);
                }
        __asm__ __volatile__("s_waitcnt lgkmcnt(0)" ::: "memory");
        bf16x8 ap[2][2];
        #pragma unroll
        for (int rg = 0; rg < 2; ++rg) {
            ap[rg][0] = ldfrag(&lP[(wave * 32 + rg * 16 + l16) * 72 + quad * 8]);
            ap[rg][1] = ldfrag(&lP[(wave * 32 + rg * 16 + l16) * 72 + 32 + quad * 8]);
        }
        bf16x8 vf[4][2];
        #pragma unroll
        for (int ni = 0; ni < 4; ++ni) {
            vf[ni][0] = ldfrag(&lV[(ni * 16 + l16) * 72 + quad * 8]);
            vf[ni][1] = ldfrag(&lV[(ni * 16 + l16) * 72 + 32 + quad * 8]);
        }
        #pragma unroll
        for (int rg = 0; rg < 2; ++rg)
            #pragma unroll
            for (int ni = 0; ni < 4; ++ni) {
                o[rg][ni] = mfma16(ap[rg][0], vf[ni][0], o[rg][ni]);
                o[rg][ni] = mfma16(ap[rg][1], vf[ni][1], o[rg][ni]);
            }
    }
    #pragma unroll
    for (int off = 1; off < 16; off <<= 1)
        #pragma unroll
        for (int rg = 0; rg < 2; ++rg)
            #pragma unroll
            for (int r = 0; r < 4; ++r)
                ps_acc[rg][r] += __shfl_xor(ps_acc[rg][r], off);
    float rl[2][4];
    #pragma unroll
    for (int rg = 0; rg < 2; ++rg)
        #pragma unroll
        for (int r = 0; r < 4; ++r) rl[rg][r] = 1.f / ps_acc[rg][r];
    #pragma unroll
    for (int rg = 0; rg < 2; ++rg)
        #pragma unroll
        for (int ni = 0; ni < 4; ++ni)
            #pragma unroll
            for (int r = 0; r < 4; ++r) {
                const int row = q0 + wave * 32 + rg * 16 + quad * 4 + r;
                attb[(size_t)(bb * 1024 + row) * 1024 + h * 64 + ni * 16 + l16] =
                    f2bf_hw(o[rg][ni][r] * rl[rg][r]);
            }
}

// ---------- residual (bf16 y) + LayerNorm ----------
__global__ __launch_bounds__(256) void ln_res(const u16* __restrict__ ybf,
                                              const u16* __restrict__ xpb,
                                              const float* __restrict__ a2,
                                              const float* __restrict__ b2,
                                              float* __restrict__ out) {
    const int row = blockIdx.x, tid = threadIdx.x;
    const size_t base = (size_t)row * 1024;
    const int j = tid * 4;
    const u16x4 yv = *(const u16x4*)&ybf[base + j];
    const u16x4 xv = *(const u16x4*)&xpb[base + j];
    float x[4] = {bf2f(yv.x) + bf2f(xv.x), bf2f(yv.y) + bf2f(xv.y),
                  bf2f(yv.z) + bf2f(xv.z), bf2f(yv.w) + bf2f(xv.w)};
    float s = 0.f, ss = 0.f;
    #pragma unroll
    for (int i = 0; i < 4; ++i) { s += x[i]; ss += x[i] * x[i]; }
    #pragma unroll
    for (int off = 1; off < 64; off <<= 1) {
        s += __shfl_xor(s, off);
        ss += __shfl_xor(ss, off);
    }
    __shared__ float rs[4], rss[4];
    const int wave = tid >> 6, lane = tid & 63;
    if (lane == 0) { rs[wave] = s; rss[wave] = ss; }
    __syncthreads();
    s = rs[0] + rs[1] + rs[2] + rs[3];
    ss = rss[0] + rss[1] + rss[2] + rss[3];
    const float mean = s * (1.f / 1024.f);
    float var = (ss - s * mean) * (1.f / 1023.f);
    var = fmaxf(var, 0.f);
    const float inv = 1.f / (sqrtf(var) + 1e-6f);
    const float4 av = *(const float4*)&a2[j];
    const float4 bv = *(const float4*)&b2[j];
    float4 ov;
    ov.x = av.x * (x[0] - mean) * inv + bv.x;
    ov.y = av.y * (x[1] - mean) * inv + bv.y;
    ov.z = av.z * (x[2] - mean) * inv + bv.z;
    ov.w = av.w * (x[3] - mean) * inv + bv.w;
    *(float4*)&out[base + j] = ov;
}

extern "C" void kernel_launch(void* const* d_in, const int* in_sizes, int n_in,
                              void* d_out, int out_size, void* d_ws, size_t ws_size,
                              hipStream_t stream) {
    (void)in_sizes; (void)n_in; (void)out_size;
    const float* y   = (const float*)d_in[0];
    const int*   msk = (const int*)d_in[1];
    const float* Wq  = (const float*)d_in[2];
    const float* bq  = (const float*)d_in[3];
    const float* Wk  = (const float*)d_in[4];
    const float* bkb = (const float*)d_in[5];
    const float* Wv  = (const float*)d_in[6];
    const float* bv  = (const float*)d_in[7];
    const float* Wm  = (const float*)d_in[8];
    const float* bm  = (const float*)d_in[9];
    const float* a2  = (const float*)d_in[10];
    const float* b2  = (const float*)d_in[11];
    float* out = (float*)d_out;

    char* ws = (char*)d_ws;
    const size_t MB = 1u << 20;
    if (ws_size < 72 * MB) return;  // need 72 MB of scratch
    u16* yb  = (u16*)(ws);             // 16 MB, stays LIVE (ln_res reads it)
    u16* wqb = (u16*)(ws + 16 * MB);   // wq/wk/wv/wm contiguous (8 MB)
    u16* wmb = (u16*)(ws + 22 * MB);
    u16* qb  = (u16*)(ws + 24 * MB);   // 16 MB (reused as bf16 xp after attn)
    u16* kb  = (u16*)(ws + 40 * MB);   // 16 MB
    u16* vb  = (u16*)(ws + 56 * MB);   // 16 MB (attn reads it live)
    u16* xpb  = qb;   // qb dead after attn

    int* idxb = (int*)d_out;                       // 8 x 1024 ints
    int* cntb = idxb + 8192;                       // 8 ints
    u16* attb = (u16*)((char*)d_out + 16 * MB);    // 16 MB

    conv_all<<<12289, 256, 0, stream>>>(y, Wq, Wk, Wv, Wm, yb, wqb,
                                        msk, idxb, cntb);

    // fused QKV: M=8192, N=3072, tile 256x256 read-ahead kernel -> 384 blocks
    gemm9<<<dim3(384), 512, 0, stream>>>(
        yb, wqb, bq, bkb, bv, qb, kb, vb, 1024, 12);

    attn<<<dim3(1024), 256, 0, stream>>>(qb, kb, vb, idxb, cntb, attb);

    // M-proj: M=8192, N=1024, tile 256x128 -> 32x8 = 256 blocks = 1/CU
    gemm8b<<<dim3(256), 512, 0, stream>>>(
        attb, wmb, bm, bm, bm, xpb, xpb, xpb, 1024, 8);

    ln_res<<<8192, 256, 0, stream>>>(yb, xpb, a2, b2, out);
}

// Round 4
// 265.685 us; speedup vs baseline: 1.0381x; 1.0381x over previous
//
#include <hip/hip_runtime.h>

#define DEVFN __device__ __forceinline__

typedef unsigned short u16;
typedef __attribute__((ext_vector_type(8))) unsigned short u16x8;
typedef __attribute__((ext_vector_type(4))) unsigned short u16x4;
typedef __attribute__((ext_vector_type(8))) __bf16 bf16x8;
typedef __attribute__((ext_vector_type(4))) float f32x4;

// ---------- helpers ----------
DEVFN u16 f2bf_hw(float f) {  // hardware RNE convert (single v_cvt)
    return __builtin_bit_cast(u16, (__bf16)f);
}

DEVFN float bf2f(u16 h) {
    unsigned u = (unsigned)h << 16;
    return __builtin_bit_cast(float, u);
}

DEVFN bf16x8 ldfrag(const u16* p) {
    return __builtin_bit_cast(bf16x8, *(const u16x8*)p);
}

DEVFN f32x4 mfma16(bf16x8 a, bf16x8 b, f32x4 c) {
    return __builtin_amdgcn_mfma_f32_16x16x32_bf16(a, b, c, 0, 0, 0);
}

// async global->LDS, 16B per lane; l must be the wave-uniform base.
// NOTE: the GLOBAL source address is per-lane (guide §5) -> row-gather OK.
DEVFN void async16(const u16* g, u16* l) {
    __builtin_amdgcn_global_load_lds(
        (const __attribute__((address_space(1))) void*)g,
        (__attribute__((address_space(3))) void*)l, 16, 0, 0);
}

// ---------- fp32->bf16 converts + mask compaction, ONE dispatch ----------
__global__ __launch_bounds__(256) void conv_all(const float* __restrict__ y,
                                                const float* __restrict__ w0,
                                                const float* __restrict__ w1,
                                                const float* __restrict__ w2,
                                                const float* __restrict__ w3,
                                                u16* __restrict__ yb,
                                                u16* __restrict__ wb,
                                                const int* __restrict__ mask,
                                                int* __restrict__ idx,
                                                int* __restrict__ cnt) {
    const int b = blockIdx.x;
    if (b >= 12288) {
        const int wave = threadIdx.x >> 6, lane = threadIdx.x & 63;
        for (int bb = wave; bb < 8; bb += 4) {
            const int* m = mask + bb * 1024;
            int* ib = idx + bb * 1024;
            int base = 0;
            for (int t = 0; t < 16; ++t) {
                const int pos = t * 64 + lane;
                const int valid = (m[pos] == 0) ? 1 : 0;
                const unsigned long long bal = __ballot(valid);
                const int pre = __popcll(bal & ((1ull << lane) - 1ull));
                if (valid) ib[base + pre] = pos;
                base += (int)__popcll(bal);
            }
            if (lane == 0) cnt[bb] = base;
            for (int i = base + lane; i < 1024; i += 64) ib[i] = 0;  // safe pad
        }
        return;
    }
    const float* src;
    u16* dst;
    int i;
    if (b < 8192) {
        src = y; dst = yb;
        i = b * 1024 + threadIdx.x * 4;
    } else {
        const int g = (b - 8192) >> 10;
        src = g == 0 ? w0 : (g == 1 ? w1 : (g == 2 ? w2 : w3));
        dst = wb + (size_t)g * 1024 * 1024;
        i = ((b - 8192) & 1023) * 1024 + threadIdx.x * 4;
    }
    const float4 v = *(const float4*)&src[i];
    u16x4 o;
    o.x = f2bf_hw(v.x); o.y = f2bf_hw(v.y);
    o.z = f2bf_hw(v.z); o.w = f2bf_hw(v.w);
    *(u16x4*)&dst[i] = o;
}

// ---------- fused Q + compacted-KV GEMM (gemm8b pipeline, role by block) ----------
// Round-4 pivot: 4 schedule structures all pinned at 26-29% MfmaUtil -> stop
// optimizing the schedule, cut the FLOPs. K/V are only ever read at the
// ~cn (~512) compacted positions per batch (attn gathers via idx); computing
// them there directly is BIT-IDENTICAL (same y rows through the same GEMM;
// pad rows idx=0 reproduce the previously-gathered pad values) and cuts QKV
// work 51.5 -> ~34 GFLOP.
//   blocks 0..255   : Q  = y       @ Wq^T  (M=8192 dense rows, N=1024)
//   blocks 256..767 : KV = y[idx]  @ [Wk;Wv]^T (per-batch M=ceil256(cn),
//                     N=2048, A rows gathered via per-lane gload_lds source)
// Pipeline = round-2 gemm8b (best measured): tile 256x128, BK=64, 8 waves
// 4Mx2N, both-sides slot-XOR swizzle (0 conflicts), counted vmcnt(4),
// K ascending in 32-chunks -> accumulation order identical (absmax stable).
__global__ __launch_bounds__(512, 2) void gemm_qkv(const u16* __restrict__ A,
                                                   const u16* __restrict__ Wq,
                                                   const u16* __restrict__ Wkv,
                                                   const float* __restrict__ bq,
                                                   const float* __restrict__ bk,
                                                   const float* __restrict__ bv,
                                                   u16* __restrict__ qb,
                                                   u16* __restrict__ kb,
                                                   u16* __restrict__ vb,
                                                   const int* __restrict__ idxb,
                                                   const int* __restrict__ cntb) {
    const int K = 1024;
    __shared__ u16 lds[2][24576];  // per buf: A [256][64] @0, B [128][64] @16384
    const int tid = threadIdx.x;
    const int wave = tid >> 6, lane = tid & 63;
    const int quad = lane >> 4, l16 = lane & 15;
    const int wm = wave >> 1, wn = wave & 1;
    // XCD-bijective chunked swizzle (768 % 8 == 0)
    const int cpx = gridDim.x >> 3;
    const int sb = (blockIdx.x & 7) * cpx + (blockIdx.x >> 3);
    // ---- role decode ----
    int m0, n0, rowbase;
    const u16* Bt;
    const float *bp0, *bp1;
    u16 *cp0, *cp1;
    const int* ib = nullptr;
    if (sb < 256) {  // Q: 32 mb x 8 nb, n-fast
        m0 = (sb >> 3) * 256;
        n0 = (sb & 7) * 128;
        rowbase = 0;
        Bt = Wq; bp0 = bq; bp1 = bq; cp0 = qb; cp1 = qb;
    } else {  // KV: b x mb x nb (nb fastest for A-panel L2 reuse)
        const int t = sb - 256;
        const int nb = t & 15, mb = (t >> 4) & 3, b = t >> 6;
        const int cn = cntb[b];
        const int pc = (cn + 255) & ~255;  // ceil256; attn reads < ceil64(cn) <= pc
        m0 = mb * 256;
        if (m0 >= pc) return;  // dead block
        n0 = nb * 128;
        rowbase = b * 1024;
        ib = idxb + b * 1024;
        Bt = Wkv; bp0 = bk; bp1 = bv; cp0 = kb; cp1 = vb;
    }
    // ---- per-lane staged A rows (4 row-groups: m0 + wave*8+sr + {0,64,128,192}) ----
    const int sr = lane >> 3, sc = lane & 7;
    const int scs = (sc ^ sr) << 3;  // pre-swizzled k-slot of the source row
    const int ar = m0 + wave * 8 + sr;
    int r0 = ar, r1 = ar + 64, r2 = ar + 128, r3 = ar + 192;
    if (ib) { r0 = ib[r0]; r1 = ib[r1]; r2 = ib[r2]; r3 = ib[r3]; }
    const u16* As0 = A + (size_t)(rowbase + r0) * K + scs;
    const u16* As1 = A + (size_t)(rowbase + r1) * K + scs;
    const u16* As2 = A + (size_t)(rowbase + r2) * K + scs;
    const u16* As3 = A + (size_t)(rowbase + r3) * K + scs;
    const u16* Bs0 = Bt + (size_t)(n0 + wave * 8 + sr) * K + scs;
    const u16* Bs1 = Bs0 + (size_t)64 * K;
    // read-side swizzled offsets (u16 units); kh=1 frag = rof ^ 32
    const int swz = (quad ^ (l16 & 7)) << 3;
    const int rofA = (wm * 64 + l16) * 64 + swz;
    const int rofB = (wn * 64 + l16) * 64 + swz;

#define STA(off, bf)                                           \
    do {                                                       \
        async16(As0 + (off), &lds[bf][0] + wave * 512);        \
        async16(As1 + (off), &lds[bf][4096] + wave * 512);     \
        async16(As2 + (off), &lds[bf][8192] + wave * 512);     \
        async16(As3 + (off), &lds[bf][12288] + wave * 512);    \
    } while (0)
#define STB(off, bf)                                           \
    do {                                                       \
        async16(Bs0 + (off), &lds[bf][16384] + wave * 512);    \
        async16(Bs1 + (off), &lds[bf][20480] + wave * 512);    \
    } while (0)

    f32x4 acc[4][4] = {};
    const int NT = K >> 6;

    // prologue: A(t0) 4 ops, B(t0) 2 ops, A(t1) 4 ops; vmcnt(4) -> t0 resident
    STA(0, 0);
    STB(0, 0);
    STA(64, 1);
    asm volatile("s_waitcnt vmcnt(4)" ::: "memory");
    __builtin_amdgcn_s_barrier();

    for (int t = 0; t < NT; ++t) {
        const int buf = t & 1;
        const u16* Ar = &lds[buf][0];
        const u16* Br = &lds[buf][16384];
        bf16x8 af[4][2], bfr[4][2];
        // ---- phase 1: A mi0-3 + B ni0-1; stage B(t+1) ----
        #pragma unroll
        for (int mi = 0; mi < 4; ++mi) {
            af[mi][0] = ldfrag(Ar + mi * 1024 + rofA);
            af[mi][1] = ldfrag(Ar + mi * 1024 + (rofA ^ 32));
        }
        #pragma unroll
        for (int ni = 0; ni < 2; ++ni) {
            bfr[ni][0] = ldfrag(Br + ni * 1024 + rofB);
            bfr[ni][1] = ldfrag(Br + ni * 1024 + (rofB ^ 32));
        }
        if (t + 1 < NT) STB((t + 1) * 64, buf ^ 1);
        __builtin_amdgcn_s_barrier();
        asm volatile("s_waitcnt lgkmcnt(0)" ::: "memory");
        __builtin_amdgcn_s_setprio(1);
        #pragma unroll
        for (int mi = 0; mi < 4; ++mi)
            #pragma unroll
            for (int ni = 0; ni < 2; ++ni) {
                acc[mi][ni] = mfma16(af[mi][0], bfr[ni][0], acc[mi][ni]);
                acc[mi][ni] = mfma16(af[mi][1], bfr[ni][1], acc[mi][ni]);
            }
        __builtin_amdgcn_s_setprio(0);
        __builtin_amdgcn_s_barrier();
        // ---- phase 2: B ni2-3; stage A(t+2) ----
        #pragma unroll
        for (int ni = 2; ni < 4; ++ni) {
            bfr[ni][0] = ldfrag(Br + ni * 1024 + rofB);
            bfr[ni][1] = ldfrag(Br + ni * 1024 + (rofB ^ 32));
        }
        if (t + 2 < NT) STA((t + 2) * 64, buf);
        __builtin_amdgcn_s_barrier();
        asm volatile("s_waitcnt lgkmcnt(0)" ::: "memory");
        __builtin_amdgcn_s_setprio(1);
        #pragma unroll
        for (int mi = 0; mi < 4; ++mi)
            #pragma unroll
            for (int ni = 2; ni < 4; ++ni) {
                acc[mi][ni] = mfma16(af[mi][0], bfr[ni][0], acc[mi][ni]);
                acc[mi][ni] = mfma16(af[mi][1], bfr[ni][1], acc[mi][ni]);
            }
        __builtin_amdgcn_s_setprio(0);
        if (t < NT - 2)
            asm volatile("s_waitcnt vmcnt(4)" ::: "memory");
        else
            asm volatile("s_waitcnt vmcnt(0)" ::: "memory");
        __builtin_amdgcn_s_barrier();
    }
#undef STA
#undef STB
    // epilogue: bias + bf16 store; col>>10 selects {q} or {k,v}
    const int wrow = m0 + wm * 64 + quad * 4;
    #pragma unroll
    for (int ni = 0; ni < 4; ++ni) {
        const int col = n0 + wn * 64 + ni * 16 + l16;
        const int cs = col >> 10;
        const int c = col & 1023;
        const float* bp = cs == 0 ? bp0 : bp1;
        u16* cp = cs == 0 ? cp0 : cp1;
        const float bb = bp[c];
        #pragma unroll
        for (int mi = 0; mi < 4; ++mi)
            #pragma unroll
            for (int r = 0; r < 4; ++r) {
                const int row = rowbase + wrow + mi * 16 + r;
                cp[(size_t)row * 1024 + c] = f2bf_hw(acc[mi][ni][r] + bb);
            }
    }
}

// ---------- pipelined 256x128 GEMM (round-2 kernel, kept for M-proj) ----------
__global__ __launch_bounds__(512, 2) void gemm8b(const u16* __restrict__ A,
                                                 const u16* __restrict__ Bt,
                                                 const float* __restrict__ b0,
                                                 const float* __restrict__ b1,
                                                 const float* __restrict__ b2,
                                                 u16* __restrict__ C0,
                                                 u16* __restrict__ C1,
                                                 u16* __restrict__ C2,
                                                 int K, int NBX) {
    __shared__ u16 lds[2][24576];  // per buf: A @0 (16384), B @16384 (8192)
    const int NT = K >> 6;
    const int tid = threadIdx.x;
    const int wave = tid >> 6, lane = tid & 63;
    const int quad = lane >> 4, l16 = lane & 15;
    const int wm = wave >> 1, wn = wave & 1;
    const int nwg = gridDim.x, cpx = nwg >> 3;
    const int sb = (blockIdx.x & 7) * cpx + (blockIdx.x >> 3);
    const int bx = sb % NBX, by = sb / NBX;
    const int m0 = by * 256, n0 = bx * 128;
    const int sr = lane >> 3, sc = lane & 7;
    const int scs = (sc ^ sr) << 3;
    const u16* Ag = A + (size_t)(m0 + wave * 8 + sr) * K + scs;
    const u16* Bg = Bt + (size_t)(n0 + wave * 8 + sr) * K + scs;
    const size_t rstep = (size_t)64 * K;
    const int swz = (quad ^ (l16 & 7)) << 3;
    const int rofA = (wm * 64 + l16) * 64 + swz;
    const int rofB = (wn * 64 + l16) * 64 + swz;

#define STAGE(gp, lp)                                        \
    do {                                                     \
        async16((gp), (lp) + wave * 512);                    \
        async16((gp) + rstep, (lp) + 4096 + wave * 512);     \
    } while (0)

    f32x4 acc[4][4] = {};

    STAGE(Ag, &lds[0][0]);
    STAGE(Ag + 2 * rstep, &lds[0][8192]);
    STAGE(Bg, &lds[0][16384]);
    STAGE(Ag + 64, &lds[1][0]);
    STAGE(Ag + 2 * rstep + 64, &lds[1][8192]);
    asm volatile("s_waitcnt vmcnt(4)" ::: "memory");
    __builtin_amdgcn_s_barrier();

    for (int t = 0; t < NT; ++t) {
        const int buf = t & 1;
        const u16* Ar = &lds[buf][0];
        const u16* Br = &lds[buf][16384];
        bf16x8 af[4][2], bfr[4][2];
        #pragma unroll
        for (int mi = 0; mi < 4; ++mi) {
            af[mi][0] = ldfrag(Ar + mi * 1024 + rofA);
            af[mi][1] = ldfrag(Ar + mi * 1024 + (rofA ^ 32));
        }
        #pragma unroll
        for (int ni = 0; ni < 2; ++ni) {
            bfr[ni][0] = ldfrag(Br + ni * 1024 + rofB);
            bfr[ni][1] = ldfrag(Br + ni * 1024 + (rofB ^ 32));
        }
        if (t + 1 < NT) STAGE(Bg + (t + 1) * 64, &lds[buf ^ 1][16384]);
        __builtin_amdgcn_s_barrier();
        asm volatile("s_waitcnt lgkmcnt(0)" ::: "memory");
        __builtin_amdgcn_s_setprio(1);
        #pragma unroll
        for (int mi = 0; mi < 4; ++mi)
            #pragma unroll
            for (int ni = 0; ni < 2; ++ni) {
                acc[mi][ni] = mfma16(af[mi][0], bfr[ni][0], acc[mi][ni]);
                acc[mi][ni] = mfma16(af[mi][1], bfr[ni][1], acc[mi][ni]);
            }
        __builtin_amdgcn_s_setprio(0);
        __builtin_amdgcn_s_barrier();
        #pragma unroll
        for (int ni = 2; ni < 4; ++ni) {
            bfr[ni][0] = ldfrag(Br + ni * 1024 + rofB);
            bfr[ni][1] = ldfrag(Br + ni * 1024 + (rofB ^ 32));
        }
        if (t + 2 < NT) {
            STAGE(Ag + (t + 2) * 64, &lds[buf][0]);
            STAGE(Ag + 2 * rstep + (t + 2) * 64, &lds[buf][8192]);
        }
        __builtin_amdgcn_s_barrier();
        asm volatile("s_waitcnt lgkmcnt(0)" ::: "memory");
        __builtin_amdgcn_s_setprio(1);
        #pragma unroll
        for (int mi = 0; mi < 4; ++mi)
            #pragma unroll
            for (int ni = 2; ni < 4; ++ni) {
                acc[mi][ni] = mfma16(af[mi][0], bfr[ni][0], acc[mi][ni]);
                acc[mi][ni] = mfma16(af[mi][1], bfr[ni][1], acc[mi][ni]);
            }
        __builtin_amdgcn_s_setprio(0);
        if (t < NT - 2)
            asm volatile("s_waitcnt vmcnt(4)" ::: "memory");
        else
            asm volatile("s_waitcnt vmcnt(0)" ::: "memory");
        __builtin_amdgcn_s_barrier();
    }
#undef STAGE
    const int wrow = m0 + wm * 64 + quad * 4;
    #pragma unroll
    for (int ni = 0; ni < 4; ++ni) {
        const int col = n0 + wn * 64 + ni * 16 + l16;
        const int cs = col >> 10;
        const int c = col & 1023;
        const float* bp = cs == 0 ? b0 : (cs == 1 ? b1 : b2);
        u16* cp = cs == 0 ? C0 : (cs == 1 ? C1 : C2);
        const float bb = bp[c];
        #pragma unroll
        for (int mi = 0; mi < 4; ++mi)
            #pragma unroll
            for (int r = 0; r < 4; ++r) {
                const int row = wrow + mi * 16 + r;
                cp[(size_t)row * 1024 + c] = f2bf_hw(acc[mi][ni][r] + bb);
            }
    }
}

// ---------- flash attention over COMPACTED K/V (now dense rows) ----------
// K/V are pre-compacted by gemm_qkv: row j of kb/vb (per batch) is the j-th
// unmasked position. Values (incl. pad rows) bit-identical to the previous
// gathered scheme; bias masks cols >= cn exactly as before.
__global__ __launch_bounds__(256) void attn(const u16* __restrict__ qb,
                                            const u16* __restrict__ kb,
                                            const u16* __restrict__ vb,
                                            const int* __restrict__ cntb,
                                            u16* __restrict__ attb) {
    const int lin = blockIdx.x;
    const int xcd = lin & 7, slot = lin >> 3;          // slot 0..127
    const int bh = xcd * 16 + (slot >> 3);
    const int q0 = (slot & 7) * 128;
    const int bb = bh >> 4, h = bh & 15;
    const int tid = threadIdx.x, wave = tid >> 6, lane = tid & 63;
    const int quad = lane >> 4, l16 = lane & 15;
    __shared__ u16 lK[64 * 72];
    __shared__ u16 lV[64 * 72];
    __shared__ u16 lP[128 * 72];

    const int cn = cntb[bb];
    const int kEnd = (cn + 63) & ~63;

    bf16x8 aq[2][2];
    #pragma unroll
    for (int rg = 0; rg < 2; ++rg) {
        const int qrow = q0 + wave * 32 + rg * 16 + l16;
        const u16* qp = qb + (size_t)(bb * 1024 + qrow) * 1024 + h * 64 + quad * 8;
        aq[rg][0] = ldfrag(qp);
        aq[rg][1] = ldfrag(qp + 32);
    }

    f32x4 o[2][4] = {};
    float ps_acc[2][4] = {};

    const int srow = tid >> 3, scol = (tid & 7) * 8;
    const u16* kbase = kb + (size_t)(bb * 1024) * 1024 + h * 64 + scol;
    const u16* vbase = vb + (size_t)(bb * 1024) * 1024 + h * 64 + scol;

    u16x8 nk0 = *(const u16x8*)(kbase + (size_t)srow * 1024);
    u16x8 nk1 = *(const u16x8*)(kbase + (size_t)(srow + 32) * 1024);
    u16x8 nv0 = *(const u16x8*)(vbase + (size_t)srow * 1024);
    u16x8 nv1 = *(const u16x8*)(vbase + (size_t)(srow + 32) * 1024);

    const float C = 0.18033688011112043f;  // 0.125 * log2(e)

    for (int kt = 0; kt < kEnd; kt += 64) {
        __syncthreads();
        *(u16x8*)&lK[srow * 72 + scol] = nk0;
        *(u16x8*)&lK[(srow + 32) * 72 + scol] = nk1;
        #pragma unroll
        for (int j = 0; j < 8; ++j) {
            lV[(scol + j) * 72 + srow] = nv0[j];
            lV[(scol + j) * 72 + srow + 32] = nv1[j];
        }
        __syncthreads();
        const int ktn = kt + 64;
        if (ktn < kEnd) {
            nk0 = *(const u16x8*)(kbase + (size_t)(ktn + srow) * 1024);
            nk1 = *(const u16x8*)(kbase + (size_t)(ktn + srow + 32) * 1024);
            nv0 = *(const u16x8*)(vbase + (size_t)(ktn + srow) * 1024);
            nv1 = *(const u16x8*)(vbase + (size_t)(ktn + srow + 32) * 1024);
        }

        bf16x8 kf[4][2];
        #pragma unroll
        for (int n = 0; n < 4; ++n) {
            kf[n][0] = ldfrag(&lK[(n * 16 + l16) * 72 + quad * 8]);
            kf[n][1] = ldfrag(&lK[(n * 16 + l16) * 72 + 32 + quad * 8]);
        }
        f32x4 s[2][4];
        #pragma unroll
        for (int rg = 0; rg < 2; ++rg)
            #pragma unroll
            for (int n = 0; n < 4; ++n) {
                f32x4 t = {};
                t = mfma16(aq[rg][0], kf[n][0], t);
                t = mfma16(aq[rg][1], kf[n][1], t);
                s[rg][n] = t;
            }
        float bias[4];
        #pragma unroll
        for (int n = 0; n < 4; ++n)
            bias[n] = (kt + n * 16 + l16 < cn) ? 0.0f : -1e9f;
        #pragma unroll
        for (int rg = 0; rg < 2; ++rg)
            #pragma unroll
            for (int n = 0; n < 4; ++n)
                #pragma unroll
                for (int r = 0; r < 4; ++r) {
                    const float p =
                        __builtin_amdgcn_exp2f(__builtin_fmaf(s[rg][n][r], C, bias[n]));
                    ps_acc[rg][r] += p;
                    lP[(wave * 32 + rg * 16 + quad * 4 + r) * 72 + n * 16 + l16] =
                        f2bf_hw(p);
                }
        __asm__ __volatile__("s_waitcnt lgkmcnt(0)" ::: "memory");
        bf16x8 ap[2][2];
        #pragma unroll
        for (int rg = 0; rg < 2; ++rg) {
            ap[rg][0] = ldfrag(&lP[(wave * 32 + rg * 16 + l16) * 72 + quad * 8]);
            ap[rg][1] = ldfrag(&lP[(wave * 32 + rg * 16 + l16) * 72 + 32 + quad * 8]);
        }
        bf16x8 vf[4][2];
        #pragma unroll
        for (int ni = 0; ni < 4; ++ni) {
            vf[ni][0] = ldfrag(&lV[(ni * 16 + l16) * 72 + quad * 8]);
            vf[ni][1] = ldfrag(&lV[(ni * 16 + l16) * 72 + 32 + quad * 8]);
        }
        #pragma unroll
        for (int rg = 0; rg < 2; ++rg)
            #pragma unroll
            for (int ni = 0; ni < 4; ++ni) {
                o[rg][ni] = mfma16(ap[rg][0], vf[ni][0], o[rg][ni]);
                o[rg][ni] = mfma16(ap[rg][1], vf[ni][1], o[rg][ni]);
            }
    }
    #pragma unroll
    for (int off = 1; off < 16; off <<= 1)
        #pragma unroll
        for (int rg = 0; rg < 2; ++rg)
            #pragma unroll
            for (int r = 0; r < 4; ++r)
                ps_acc[rg][r] += __shfl_xor(ps_acc[rg][r], off);
    float rl[2][4];
    #pragma unroll
    for (int rg = 0; rg < 2; ++rg)
        #pragma unroll
        for (int r = 0; r < 4; ++r) rl[rg][r] = 1.f / ps_acc[rg][r];
    #pragma unroll
    for (int rg = 0; rg < 2; ++rg)
        #pragma unroll
        for (int ni = 0; ni < 4; ++ni)
            #pragma unroll
            for (int r = 0; r < 4; ++r) {
                const int row = q0 + wave * 32 + rg * 16 + quad * 4 + r;
                attb[(size_t)(bb * 1024 + row) * 1024 + h * 64 + ni * 16 + l16] =
                    f2bf_hw(o[rg][ni][r] * rl[rg][r]);
            }
}

// ---------- residual (bf16 y) + LayerNorm ----------
__global__ __launch_bounds__(256) void ln_res(const u16* __restrict__ ybf,
                                              const u16* __restrict__ xpb,
                                              const float* __restrict__ a2,
                                              const float* __restrict__ b2,
                                              float* __restrict__ out) {
    const int row = blockIdx.x, tid = threadIdx.x;
    const size_t base = (size_t)row * 1024;
    const int j = tid * 4;
    const u16x4 yv = *(const u16x4*)&ybf[base + j];
    const u16x4 xv = *(const u16x4*)&xpb[base + j];
    float x[4] = {bf2f(yv.x) + bf2f(xv.x), bf2f(yv.y) + bf2f(xv.y),
                  bf2f(yv.z) + bf2f(xv.z), bf2f(yv.w) + bf2f(xv.w)};
    float s = 0.f, ss = 0.f;
    #pragma unroll
    for (int i = 0; i < 4; ++i) { s += x[i]; ss += x[i] * x[i]; }
    #pragma unroll
    for (int off = 1; off < 64; off <<= 1) {
        s += __shfl_xor(s, off);
        ss += __shfl_xor(ss, off);
    }
    __shared__ float rs[4], rss[4];
    const int wave = tid >> 6, lane = tid & 63;
    if (lane == 0) { rs[wave] = s; rss[wave] = ss; }
    __syncthreads();
    s = rs[0] + rs[1] + rs[2] + rs[3];
    ss = rss[0] + rss[1] + rss[2] + rss[3];
    const float mean = s * (1.f / 1024.f);
    float var = (ss - s * mean) * (1.f / 1023.f);
    var = fmaxf(var, 0.f);
    const float inv = 1.f / (sqrtf(var) + 1e-6f);
    const float4 av = *(const float4*)&a2[j];
    const float4 bv = *(const float4*)&b2[j];
    float4 ov;
    ov.x = av.x * (x[0] - mean) * inv + bv.x;
    ov.y = av.y * (x[1] - mean) * inv + bv.y;
    ov.z = av.z * (x[2] - mean) * inv + bv.z;
    ov.w = av.w * (x[3] - mean) * inv + bv.w;
    *(float4*)&out[base + j] = ov;
}

extern "C" void kernel_launch(void* const* d_in, const int* in_sizes, int n_in,
                              void* d_out, int out_size, void* d_ws, size_t ws_size,
                              hipStream_t stream) {
    (void)in_sizes; (void)n_in; (void)out_size;
    const float* y   = (const float*)d_in[0];
    const int*   msk = (const int*)d_in[1];
    const float* Wq  = (const float*)d_in[2];
    const float* bq  = (const float*)d_in[3];
    const float* Wk  = (const float*)d_in[4];
    const float* bkb = (const float*)d_in[5];
    const float* Wv  = (const float*)d_in[6];
    const float* bv  = (const float*)d_in[7];
    const float* Wm  = (const float*)d_in[8];
    const float* bm  = (const float*)d_in[9];
    const float* a2  = (const float*)d_in[10];
    const float* b2  = (const float*)d_in[11];
    float* out = (float*)d_out;

    char* ws = (char*)d_ws;
    const size_t MB = 1u << 20;
    if (ws_size < 72 * MB) return;  // need 72 MB of scratch
    u16* yb  = (u16*)(ws);             // 16 MB, stays LIVE (ln_res reads it)
    u16* wqb = (u16*)(ws + 16 * MB);   // wq/wk/wv/wm contiguous (8 MB)
    u16* wmb = (u16*)(ws + 22 * MB);
    u16* qb  = (u16*)(ws + 24 * MB);   // 16 MB (reused as bf16 xp after attn)
    u16* kb  = (u16*)(ws + 40 * MB);   // 16 MB
    u16* vb  = (u16*)(ws + 56 * MB);   // 16 MB (attn reads it live)
    u16* xpb  = qb;   // qb dead after attn

    int* idxb = (int*)d_out;                       // 8 x 1024 ints
    int* cntb = idxb + 8192;                       // 8 ints
    u16* attb = (u16*)((char*)d_out + 16 * MB);    // 16 MB

    conv_all<<<12289, 256, 0, stream>>>(y, Wq, Wk, Wv, Wm, yb, wqb,
                                        msk, idxb, cntb);

    // fused Q + compacted-KV GEMM: 256 Q-blocks + 512 KV-blocks (many exit
    // early on cnt). Wkv = wqb + 1M u16 (Wk,Wv rows contiguous).
    gemm_qkv<<<dim3(768), 512, 0, stream>>>(
        yb, wqb, wqb + 1024 * 1024, bq, bkb, bv, qb, kb, vb, idxb, cntb);

    attn<<<dim3(1024), 256, 0, stream>>>(qb, kb, vb, cntb, attb);

    // M-proj: M=8192, N=1024, tile 256x128 -> 32x8 = 256 blocks = 1/CU
    gemm8b<<<dim3(256), 512, 0, stream>>>(
        attb, wmb, bm, bm, bm, xpb, xpb, xpb, 1024, 8);

    ln_res<<<8192, 256, 0, stream>>>(yb, xpb, a2, b2, out);
}